// Round 4
// baseline (371.011 us; speedup 1.0000x reference)
//
#include <hip/hip_runtime.h>

#define IMG_W 512
#define IMG_H 512
#define N_IMG 48            // 16 batch * 3 channels
#define TILE_W 64
#define TILE_H 32
#define RAD 5
#define KS 11
#define HALO_H (TILE_H + 2*RAD)   // 42
#define W4 (TILE_W/4)             // 16 float4 per tile row
#define NBLOCKS (8*16*48)         // 6144

__global__ void ssim_zero_acc(double* acc) {
    if (threadIdx.x == 0) { acc[0] = 0.0; ((unsigned int*)(acc + 1))[0] = 0u; }
}

__device__ inline void fma4(float4& a, float w, const float4& v) {
    a.x += w * v.x; a.y += w * v.y; a.z += w * v.z; a.w += w * v.w;
}

__device__ inline float ssim1(float m1, float m2, float epp, float ett, float ept) {
    const float C1 = 1e-4f, C2 = 9e-4f;
    const float m1s = m1 * m1, m2s = m2 * m2, m12 = m1 * m2;
    const float num = (2.f * m12 + C1) * (2.f * (ept - m12) + C2);
    const float den = (m1s + m2s + C1) * ((epp - m1s) + (ett - m2s) + C2);
    return num * __builtin_amdgcn_rcpf(den);   // rel err ~1e-7 << 2e-2 threshold
}

// RNE-pack two fp32 into a bf16 pair (values are finite, non-NaN here)
__device__ inline unsigned int bf16pair(float a, float b) {
    unsigned int ua = __float_as_uint(a), ub = __float_as_uint(b);
    ua = (ua + 0x7fffu + ((ua >> 16) & 1u)) >> 16;
    ub = (ub + 0x7fffu + ((ub >> 16) & 1u)) >> 16;
    return ua | (ub << 16);
}

// unpack 4 bf16 (uint2) -> float4: bf16->f32 is a 16-bit shift / mask
__device__ inline float4 bf16x4_to_f4(uint2 u) {
    float4 f;
    f.x = __uint_as_float(u.x << 16);
    f.y = __uint_as_float(u.x & 0xffff0000u);
    f.z = __uint_as_float(u.y << 16);
    f.w = __uint_as_float(u.y & 0xffff0000u);
    return f;
}

__global__ __launch_bounds__(256, 4)
void ssim_main(const float* __restrict__ pred, const float* __restrict__ targ,
               double* __restrict__ acc, float* __restrict__ out)
{
    // mu inputs fp32 (2 x 10752 B), product arrays bf16 (3 x 5376 B) = 37632 B
    // -> 4 blocks/CU (150528 of 163840 B), 16 waves/CU
    __shared__ float4 s_p [HALO_H][W4];
    __shared__ float4 s_t [HALO_H][W4];
    __shared__ uint2  s_pp[HALO_H][W4];
    __shared__ uint2  s_tt[HALO_H][W4];
    __shared__ uint2  s_pt[HALO_H][W4];
    __shared__ float wave_part[4];

    // Gaussian weights (sigma=1.5, normalized)
    float wt[KS];
    {
        float ssum = 0.f;
        #pragma unroll
        for (int i = 0; i < KS; ++i) {
            const float d = (float)(i - RAD);
            wt[i] = expf(-d * d / 4.5f);
            ssum += wt[i];
        }
        #pragma unroll
        for (int i = 0; i < KS; ++i) wt[i] /= ssum;
    }

    const int tid  = threadIdx.x;
    const int col0 = blockIdx.x * TILE_W;
    const int row0 = blockIdx.y * TILE_H;
    const bool edge = (blockIdx.x == 0) || (blockIdx.x == IMG_W / TILE_W - 1);
    const long img = blockIdx.z;
    const float* __restrict__ p = pred + img * (long)(IMG_H * IMG_W);
    const float* __restrict__ t = targ + img * (long)(IMG_H * IMG_W);

    // ---- Phase 1: horizontal 11-tap conv of {p, t, p^2, t^2, p*t} ----
    for (int idx = tid; idx < HALO_H * W4; idx += 256) {
        const int rl = idx >> 4;
        const int c4 = idx & 15;
        const int grow = row0 - RAD + rl;
        float oo[5][4];
        #pragma unroll
        for (int a = 0; a < 5; ++a)
            #pragma unroll
            for (int k = 0; k < 4; ++k) oo[a][k] = 0.f;

        if (grow >= 0 && grow < IMG_H) {
            const float* __restrict__ prow = p + (long)grow * IMG_W;
            const float* __restrict__ trow = t + (long)grow * IMG_W;
            const int base = col0 + c4 * 4 - 8;   // 16B aligned; window rp[3..16]

            float rp[20] __attribute__((aligned(16)));
            float rt[20] __attribute__((aligned(16)));
            if (!edge) {
                #pragma unroll
                for (int g = 0; g < 5; ++g) {
                    *(float4*)&rp[4 * g] = *(const float4*)&prow[base + 4 * g];
                    *(float4*)&rt[4 * g] = *(const float4*)&trow[base + 4 * g];
                }
            } else {
                #pragma unroll
                for (int g = 0; g < 5; ++g) {
                    const int gc = base + 4 * g;
                    if (gc >= 0 && gc + 4 <= IMG_W) {
                        *(float4*)&rp[4 * g] = *(const float4*)&prow[gc];
                        *(float4*)&rt[4 * g] = *(const float4*)&trow[gc];
                    } else {
                        #pragma unroll
                        for (int e = 0; e < 4; ++e) {
                            const int c = gc + e;
                            const bool ok = (c >= 0) && (c < IMG_W);
                            rp[4 * g + e] = ok ? prow[c] : 0.f;
                            rt[4 * g + e] = ok ? trow[c] : 0.f;
                        }
                    }
                }
            }
            // products once per source element (window spans rp[3..16])
            float vp[14], vt[14], vpp[14], vtt[14], vpt[14];
            #pragma unroll
            for (int i = 0; i < 14; ++i) {
                vp[i]  = rp[i + 3];
                vt[i]  = rt[i + 3];
                vpp[i] = vp[i] * vp[i];
                vtt[i] = vt[i] * vt[i];
                vpt[i] = vp[i] * vt[i];
            }
            #pragma unroll
            for (int j = 0; j < KS; ++j) {
                const float wj = wt[j];
                #pragma unroll
                for (int k = 0; k < 4; ++k) {
                    oo[0][k] += wj * vp [k + j];
                    oo[1][k] += wj * vt [k + j];
                    oo[2][k] += wj * vpp[k + j];
                    oo[3][k] += wj * vtt[k + j];
                    oo[4][k] += wj * vpt[k + j];
                }
            }
        }
        s_p[rl][c4] = make_float4(oo[0][0], oo[0][1], oo[0][2], oo[0][3]);
        s_t[rl][c4] = make_float4(oo[1][0], oo[1][1], oo[1][2], oo[1][3]);
        s_pp[rl][c4] = make_uint2(bf16pair(oo[2][0], oo[2][1]), bf16pair(oo[2][2], oo[2][3]));
        s_tt[rl][c4] = make_uint2(bf16pair(oo[3][0], oo[3][1]), bf16pair(oo[3][2], oo[3][3]));
        s_pt[rl][c4] = make_uint2(bf16pair(oo[4][0], oo[4][1]), bf16pair(oo[4][2], oo[4][3]));
    }
    __syncthreads();

    // ---- Phase 2: vertical 11-tap conv, each thread does a 2-row x 4-col patch ----
    const int c4  = tid & 15;
    const int r2  = tid >> 4;       // 0..15
    const int rr0 = r2 * 2;         // output rows rr0, rr0+1 (halo rows rr0 .. rr0+11)

    float4 acc0[5], acc1[5];
    #pragma unroll
    for (int a = 0; a < 5; ++a) {
        acc0[a] = make_float4(0.f, 0.f, 0.f, 0.f);
        acc1[a] = make_float4(0.f, 0.f, 0.f, 0.f);
    }
    #pragma unroll
    for (int j = 0; j < 12; ++j) {
        float4 v[5];
        v[0] = s_p[rr0 + j][c4];
        v[1] = s_t[rr0 + j][c4];
        v[2] = bf16x4_to_f4(s_pp[rr0 + j][c4]);
        v[3] = bf16x4_to_f4(s_tt[rr0 + j][c4]);
        v[4] = bf16x4_to_f4(s_pt[rr0 + j][c4]);
        if (j < 11) {
            const float w = wt[j];
            #pragma unroll
            for (int a = 0; a < 5; ++a) fma4(acc0[a], w, v[a]);
        }
        if (j >= 1) {
            const float w = wt[j - 1];
            #pragma unroll
            for (int a = 0; a < 5; ++a) fma4(acc1[a], w, v[a]);
        }
    }
    float lsum = 0.f;
    lsum += ssim1(acc0[0].x, acc0[1].x, acc0[2].x, acc0[3].x, acc0[4].x);
    lsum += ssim1(acc0[0].y, acc0[1].y, acc0[2].y, acc0[3].y, acc0[4].y);
    lsum += ssim1(acc0[0].z, acc0[1].z, acc0[2].z, acc0[3].z, acc0[4].z);
    lsum += ssim1(acc0[0].w, acc0[1].w, acc0[2].w, acc0[3].w, acc0[4].w);
    lsum += ssim1(acc1[0].x, acc1[1].x, acc1[2].x, acc1[3].x, acc1[4].x);
    lsum += ssim1(acc1[0].y, acc1[1].y, acc1[2].y, acc1[3].y, acc1[4].y);
    lsum += ssim1(acc1[0].z, acc1[1].z, acc1[2].z, acc1[3].z, acc1[4].z);
    lsum += ssim1(acc1[0].w, acc1[1].w, acc1[2].w, acc1[3].w, acc1[4].w);

    // ---- Block reduction -> one double atomic; last block finalizes ----
    #pragma unroll
    for (int off = 32; off > 0; off >>= 1)
        lsum += __shfl_down(lsum, off, 64);
    const int wave = tid >> 6;
    const int lane = tid & 63;
    if (lane == 0) wave_part[wave] = lsum;
    __syncthreads();
    if (tid == 0) {
        const float bs = wave_part[0] + wave_part[1] + wave_part[2] + wave_part[3];
        atomicAdd(acc, (double)bs);
        __threadfence();                               // release our contribution
        unsigned int* cnt = (unsigned int*)(acc + 1);
        const unsigned int old = atomicAdd(cnt, 1u);
        if (old == NBLOCKS - 1) {                      // all contributions visible
            const double tot = atomicAdd(acc, 0.0);    // device-coherent read
            const double n = (double)N_IMG * (double)IMG_H * (double)IMG_W;
            out[0] = (float)(1.0 - tot / n);
        }
    }
}

extern "C" void kernel_launch(void* const* d_in, const int* in_sizes, int n_in,
                              void* d_out, int out_size, void* d_ws, size_t ws_size,
                              hipStream_t stream) {
    const float* pred = (const float*)d_in[0];
    const float* targ = (const float*)d_in[1];
    float* out  = (float*)d_out;
    double* acc = (double*)d_ws;   // [0]=sum (double), [1]=block counter (uint)

    hipLaunchKernelGGL(ssim_zero_acc, dim3(1), dim3(1), 0, stream, acc);
    dim3 grid(IMG_W / TILE_W, IMG_H / TILE_H, N_IMG);   // (8, 16, 48)
    hipLaunchKernelGGL(ssim_main, grid, dim3(256), 0, stream, pred, targ, acc, out);
}

// Round 5
// 192.239 us; speedup vs baseline: 1.9299x; 1.9299x over previous
//
#include <hip/hip_runtime.h>

#define IMG_W 512
#define IMG_H 512
#define N_IMG 48            // 16 batch * 3 channels
#define TILE_W 64
#define TILE_H 32
#define RAD 5
#define KS 11
#define HALO_H (TILE_H + 2*RAD)   // 42
#define W4 (TILE_W/4)             // 16 float4 per tile row

__global__ void ssim_zero_acc(double* acc) {
    if (threadIdx.x == 0) acc[0] = 0.0;
}

__device__ inline void fma4(float4& a, float w, const float4& v) {
    a.x += w * v.x; a.y += w * v.y; a.z += w * v.z; a.w += w * v.w;
}

__device__ inline float ssim1(float m1, float m2, float epp, float ett, float ept) {
    const float C1 = 1e-4f, C2 = 9e-4f;
    const float m1s = m1 * m1, m2s = m2 * m2, m12 = m1 * m2;
    const float num = (2.f * m12 + C1) * (2.f * (ept - m12) + C2);
    const float den = (m1s + m2s + C1) * ((epp - m1s) + (ett - m2s) + C2);
    return num * __builtin_amdgcn_rcpf(den);   // rel err ~1e-7 << 2e-2 threshold
}

// RNE-pack two fp32 into a bf16 pair (values finite, non-NaN here)
__device__ inline unsigned int bf16pair(float a, float b) {
    unsigned int ua = __float_as_uint(a), ub = __float_as_uint(b);
    ua = (ua + 0x7fffu + ((ua >> 16) & 1u)) >> 16;
    ub = (ub + 0x7fffu + ((ub >> 16) & 1u)) >> 16;
    return ua | (ub << 16);
}

// unpack 4 bf16 (uint2) -> float4 (bf16->f32 = shift/mask)
__device__ inline float4 bf16x4_to_f4(uint2 u) {
    float4 f;
    f.x = __uint_as_float(u.x << 16);
    f.y = __uint_as_float(u.x & 0xffff0000u);
    f.z = __uint_as_float(u.y << 16);
    f.w = __uint_as_float(u.y & 0xffff0000u);
    return f;
}

// NOTE: NO __threadfence / completion-counter in this kernel. R3/R4 showed the
// per-block agent-scope fence (needed for a fold-in finalize) forces XCD-L2
// writeback/invalidate 6144 times per dispatch -> all halo re-reads fall from
// L2 to L3, VALUBusy collapses (45%->15-22%), dur 117->~280 us. Separate tiny
// finalize kernel is free (end-to-end gap is fixed harness overhead either way).
__global__ __launch_bounds__(256, 4)
void ssim_main(const float* __restrict__ pred, const float* __restrict__ targ,
               double* __restrict__ acc)
{
    // mu inputs fp32 (2 x 10752 B), product arrays bf16 (3 x 5376 B) = 37632 B
    // -> 4 blocks/CU (151 KB of 160 KB), 16 waves/CU
    __shared__ float4 s_p [HALO_H][W4];
    __shared__ float4 s_t [HALO_H][W4];
    __shared__ uint2  s_pp[HALO_H][W4];
    __shared__ uint2  s_tt[HALO_H][W4];
    __shared__ uint2  s_pt[HALO_H][W4];
    __shared__ float wave_part[4];

    // Gaussian weights (sigma=1.5, normalized)
    float wt[KS];
    {
        float ssum = 0.f;
        #pragma unroll
        for (int i = 0; i < KS; ++i) {
            const float d = (float)(i - RAD);
            wt[i] = expf(-d * d / 4.5f);
            ssum += wt[i];
        }
        #pragma unroll
        for (int i = 0; i < KS; ++i) wt[i] /= ssum;
    }

    const int tid  = threadIdx.x;
    const int col0 = blockIdx.x * TILE_W;
    const int row0 = blockIdx.y * TILE_H;
    const bool edge = (blockIdx.x == 0) || (blockIdx.x == IMG_W / TILE_W - 1);
    const long img = blockIdx.z;
    const float* __restrict__ p = pred + img * (long)(IMG_H * IMG_W);
    const float* __restrict__ t = targ + img * (long)(IMG_H * IMG_W);

    // ---- Phase 1: horizontal 11-tap conv of {p, t, p^2, t^2, p*t} ----
    for (int idx = tid; idx < HALO_H * W4; idx += 256) {
        const int rl = idx >> 4;
        const int c4 = idx & 15;
        const int grow = row0 - RAD + rl;
        float oo[5][4];
        #pragma unroll
        for (int a = 0; a < 5; ++a)
            #pragma unroll
            for (int k = 0; k < 4; ++k) oo[a][k] = 0.f;

        if (grow >= 0 && grow < IMG_H) {
            const float* __restrict__ prow = p + (long)grow * IMG_W;
            const float* __restrict__ trow = t + (long)grow * IMG_W;
            const int base = col0 + c4 * 4 - 8;   // 16B aligned; window rp[3..16]

            float rp[20] __attribute__((aligned(16)));
            float rt[20] __attribute__((aligned(16)));
            if (!edge) {
                #pragma unroll
                for (int g = 0; g < 5; ++g) {
                    *(float4*)&rp[4 * g] = *(const float4*)&prow[base + 4 * g];
                    *(float4*)&rt[4 * g] = *(const float4*)&trow[base + 4 * g];
                }
            } else {
                #pragma unroll
                for (int g = 0; g < 5; ++g) {
                    const int gc = base + 4 * g;
                    if (gc >= 0 && gc + 4 <= IMG_W) {
                        *(float4*)&rp[4 * g] = *(const float4*)&prow[gc];
                        *(float4*)&rt[4 * g] = *(const float4*)&trow[gc];
                    } else {
                        #pragma unroll
                        for (int e = 0; e < 4; ++e) {
                            const int c = gc + e;
                            const bool ok = (c >= 0) && (c < IMG_W);
                            rp[4 * g + e] = ok ? prow[c] : 0.f;
                            rt[4 * g + e] = ok ? trow[c] : 0.f;
                        }
                    }
                }
            }
            float vp[14], vt[14], vpp[14], vtt[14], vpt[14];
            #pragma unroll
            for (int i = 0; i < 14; ++i) {
                vp[i]  = rp[i + 3];
                vt[i]  = rt[i + 3];
                vpp[i] = vp[i] * vp[i];
                vtt[i] = vt[i] * vt[i];
                vpt[i] = vp[i] * vt[i];
            }
            #pragma unroll
            for (int j = 0; j < KS; ++j) {
                const float wj = wt[j];
                #pragma unroll
                for (int k = 0; k < 4; ++k) {
                    oo[0][k] += wj * vp [k + j];
                    oo[1][k] += wj * vt [k + j];
                    oo[2][k] += wj * vpp[k + j];
                    oo[3][k] += wj * vtt[k + j];
                    oo[4][k] += wj * vpt[k + j];
                }
            }
        }
        s_p [rl][c4] = make_float4(oo[0][0], oo[0][1], oo[0][2], oo[0][3]);
        s_t [rl][c4] = make_float4(oo[1][0], oo[1][1], oo[1][2], oo[1][3]);
        s_pp[rl][c4] = make_uint2(bf16pair(oo[2][0], oo[2][1]), bf16pair(oo[2][2], oo[2][3]));
        s_tt[rl][c4] = make_uint2(bf16pair(oo[3][0], oo[3][1]), bf16pair(oo[3][2], oo[3][3]));
        s_pt[rl][c4] = make_uint2(bf16pair(oo[4][0], oo[4][1]), bf16pair(oo[4][2], oo[4][3]));
    }
    __syncthreads();

    // ---- Phase 2: vertical 11-tap conv, 2 rows x 4 cols per thread ----
    const int c4  = tid & 15;
    const int r2  = tid >> 4;       // 0..15
    const int rr0 = r2 * 2;         // output rows rr0, rr0+1

    float4 acc0[5], acc1[5];
    #pragma unroll
    for (int a = 0; a < 5; ++a) {
        acc0[a] = make_float4(0.f, 0.f, 0.f, 0.f);
        acc1[a] = make_float4(0.f, 0.f, 0.f, 0.f);
    }
    #pragma unroll
    for (int j = 0; j < 12; ++j) {
        float4 v[5];
        v[0] = s_p[rr0 + j][c4];
        v[1] = s_t[rr0 + j][c4];
        v[2] = bf16x4_to_f4(s_pp[rr0 + j][c4]);
        v[3] = bf16x4_to_f4(s_tt[rr0 + j][c4]);
        v[4] = bf16x4_to_f4(s_pt[rr0 + j][c4]);
        if (j < 11) {
            const float w = wt[j];
            #pragma unroll
            for (int a = 0; a < 5; ++a) fma4(acc0[a], w, v[a]);
        }
        if (j >= 1) {
            const float w = wt[j - 1];
            #pragma unroll
            for (int a = 0; a < 5; ++a) fma4(acc1[a], w, v[a]);
        }
    }
    float lsum = 0.f;
    lsum += ssim1(acc0[0].x, acc0[1].x, acc0[2].x, acc0[3].x, acc0[4].x);
    lsum += ssim1(acc0[0].y, acc0[1].y, acc0[2].y, acc0[3].y, acc0[4].y);
    lsum += ssim1(acc0[0].z, acc0[1].z, acc0[2].z, acc0[3].z, acc0[4].z);
    lsum += ssim1(acc0[0].w, acc0[1].w, acc0[2].w, acc0[3].w, acc0[4].w);
    lsum += ssim1(acc1[0].x, acc1[1].x, acc1[2].x, acc1[3].x, acc1[4].x);
    lsum += ssim1(acc1[0].y, acc1[1].y, acc1[2].y, acc1[3].y, acc1[4].y);
    lsum += ssim1(acc1[0].z, acc1[1].z, acc1[2].z, acc1[3].z, acc1[4].z);
    lsum += ssim1(acc1[0].w, acc1[1].w, acc1[2].w, acc1[3].w, acc1[4].w);

    // ---- Block reduction -> one double atomic per block ----
    #pragma unroll
    for (int off = 32; off > 0; off >>= 1)
        lsum += __shfl_down(lsum, off, 64);
    const int wave = tid >> 6;
    const int lane = tid & 63;
    if (lane == 0) wave_part[wave] = lsum;
    __syncthreads();
    if (tid == 0) {
        const float bs = wave_part[0] + wave_part[1] + wave_part[2] + wave_part[3];
        atomicAdd(acc, (double)bs);
    }
}

__global__ void ssim_final(const double* __restrict__ acc, float* __restrict__ out) {
    if (threadIdx.x == 0) {
        const double n = (double)N_IMG * (double)IMG_H * (double)IMG_W;
        out[0] = (float)(1.0 - acc[0] / n);
    }
}

extern "C" void kernel_launch(void* const* d_in, const int* in_sizes, int n_in,
                              void* d_out, int out_size, void* d_ws, size_t ws_size,
                              hipStream_t stream) {
    const float* pred = (const float*)d_in[0];
    const float* targ = (const float*)d_in[1];
    float* out  = (float*)d_out;
    double* acc = (double*)d_ws;

    hipLaunchKernelGGL(ssim_zero_acc, dim3(1), dim3(1), 0, stream, acc);
    dim3 grid(IMG_W / TILE_W, IMG_H / TILE_H, N_IMG);   // (8, 16, 48)
    hipLaunchKernelGGL(ssim_main, grid, dim3(256), 0, stream, pred, targ, acc);
    hipLaunchKernelGGL(ssim_final, dim3(1), dim3(1), 0, stream, acc, out);
}